// Round 4
// baseline (1282.445 us; speedup 1.0000x reference)
//
#include <hip/hip_runtime.h>
#include <hip/hip_fp16.h>

// ---------------------------------------------------------------------------
// TimmPnPNystromAttention  (B=32, N=1025, C=768, H=12, Dh=64, landmarks=64)
// Round 4: fuse maxc into t1 (online softmax), split t1 over n (384x6 blocks),
// fdot2 (v_dot2_f32_f16) + fp16 LDS in t1 and prod phase1.
//
// d_out: [Xh fp16 | Qh fp16] ; Xh region reused for T1 partials after qkv gemm
// ws: Kh | Vh (fp16; CTXh aliases Kh) | fp32 smalls | WT fp16
// ---------------------------------------------------------------------------

constexpr int kN  = 1025;
constexpr int kNT = 32 * kN;      // 32800 tokens
constexpr int kBH = 32 * 12;      // 384

constexpr size_t QSZ  = (size_t)kBH * kN * 64;   // 25190400 == out_size
constexpr size_t QMSZ = (size_t)kBH * 65 * 64;   // 1597440
constexpr size_t SBSZ = (size_t)kBH * 65 * 65;   // 1622400
constexpr int kSplits = 6;                        // t1 n-splits (tiles 3,3,3,3,3,2)

typedef _Float16 f16x8 __attribute__((ext_vector_type(8)));
typedef float    f32x4 __attribute__((ext_vector_type(4)));
typedef _Float16 h2v __attribute__((ext_vector_type(2)));
typedef _Float16 h4v __attribute__((ext_vector_type(4)));

#define GLDS(gp, lp) __builtin_amdgcn_global_load_lds( \
    (const __attribute__((address_space(1))) void*)(gp), \
    (__attribute__((address_space(3))) void*)(lp), 16, 0, 0)

__device__ __forceinline__ float fdot2f(h2v a, h2v b, float c) {
#if __has_builtin(__builtin_amdgcn_fdot2)
    return __builtin_amdgcn_fdot2(a, b, c, false);
#else
    return fmaf((float)a[0], (float)b[0], fmaf((float)a[1], (float)b[1], c));
#endif
}
__device__ __forceinline__ float fdot4f(h4v a, h4v b, float c) {
    h2v al = __builtin_shufflevector(a, a, 0, 1);
    h2v ah = __builtin_shufflevector(a, a, 2, 3);
    h2v bl = __builtin_shufflevector(b, b, 0, 1);
    h2v bh = __builtin_shufflevector(b, b, 2, 3);
    return fdot2f(ah, bh, fdot2f(al, bl, c));
}

// ---------------- K0a: fp32 -> fp16 elementwise (X) -------------------------
__global__ __launch_bounds__(256) void cvt_f32_f16(
    const float* __restrict__ src, __half* __restrict__ dst, int n4)
{
    int i = blockIdx.x * 256 + threadIdx.x;
    if (i < n4) {
        float4 v = ((const float4*)src)[i];
        ((__half2*)dst)[2 * i]     = __floats2half2_rn(v.x, v.y);
        ((__half2*)dst)[2 * i + 1] = __floats2half2_rn(v.z, v.w);
    }
}

// ---------------- K0b: W (rows x cols, fp32) -> WT (cols x rows, fp16) ------
__global__ __launch_bounds__(256) void cvt_transpose(
    const float* __restrict__ W, __half* __restrict__ WT, int rows, int cols)
{
    __shared__ float tile[32][33];
    const int n0 = blockIdx.x * 32, k0 = blockIdx.y * 32;
#pragma unroll
    for (int i = 0; i < 4; ++i)
        tile[threadIdx.y + i * 8][threadIdx.x] =
            W[(size_t)(k0 + threadIdx.y + i * 8) * cols + n0 + threadIdx.x];
    __syncthreads();
#pragma unroll
    for (int i = 0; i < 4; ++i)
        WT[(size_t)(n0 + threadIdx.y + i * 8) * rows + k0 + threadIdx.x] =
            __float2half_rn(tile[threadIdx.x][threadIdx.y + i * 8]);
}

// ---------------- K1/K9: fp16 MFMA GEMM, 128x128 tile, BK=64 ----------------
template<int MODE>
__global__ __launch_bounds__(256) void gemm_mfma(
    const __half* __restrict__ A, const __half* __restrict__ Bt,
    const float* __restrict__ bias,
    float* __restrict__ OutF, __half* __restrict__ Qo,
    __half* __restrict__ Ko, __half* __restrict__ Vo)
{
    __shared__ _Float16 As[128 * 64];
    __shared__ _Float16 Bs[128 * 64];
    const int t  = threadIdx.x;
    const int w  = t >> 6, L = t & 63;
    const int q  = L >> 4, ln = L & 15;
    const int wm = w >> 1, wn = w & 1;
    const int cb = blockIdx.x * 128, rb = blockIdx.y * 128;

    f32x4 acc[4][4];
#pragma unroll
    for (int i = 0; i < 4; ++i)
#pragma unroll
        for (int j = 0; j < 4; ++j) acc[i][j] = (f32x4)0.f;

    const int srow = L >> 3;
    const int sc   = L & 7;

    for (int kt = 0; kt < 12; ++kt) {
        const int k0 = kt * 64;
        __syncthreads();
#pragma unroll
        for (int i = 0; i < 4; ++i) {
            const int r0  = w * 32 + i * 8;
            const int row = r0 + srow;
            const int g   = sc ^ (row & 7);
            if (rb + row < kNT)
                GLDS(A + (size_t)(rb + row) * 768 + k0 + g * 8, &As[r0 * 64]);
            GLDS(Bt + (size_t)(cb + row) * 768 + k0 + g * 8, &Bs[r0 * 64]);
        }
        __syncthreads();
#pragma unroll
        for (int kc = 0; kc < 2; ++kc) {
            f16x8 af[4], bf[4];
#pragma unroll
            for (int im = 0; im < 4; ++im) {
                const int m    = wm * 64 + im * 16 + ln;
                const int slot = (kc * 4 + q) ^ (m & 7);
                af[im] = *(const f16x8*)&As[m * 64 + slot * 8];
            }
#pragma unroll
            for (int in = 0; in < 4; ++in) {
                const int n    = wn * 64 + in * 16 + ln;
                const int slot = (kc * 4 + q) ^ (n & 7);
                bf[in] = *(const f16x8*)&Bs[n * 64 + slot * 8];
            }
#pragma unroll
            for (int im = 0; im < 4; ++im)
#pragma unroll
                for (int in = 0; in < 4; ++in)
                    acc[im][in] = __builtin_amdgcn_mfma_f32_16x16x32_f16(
                        af[im], bf[in], acc[im][in], 0, 0, 0);
        }
    }

    float bcol[4];
#pragma unroll
    for (int in = 0; in < 4; ++in) bcol[in] = bias[cb + wn * 64 + in * 16 + ln];

    if (MODE == 0) {
#pragma unroll
        for (int in = 0; in < 4; ++in) {
            const int Ncol  = cb + wn * 64 + in * 16 + ln;
            const int which = Ncol / 768;
            const int cm    = Ncol - which * 768;
            const int h     = cm >> 6, d0 = cm & 63;
            __half* dst = (which == 0) ? Qo : (which == 1) ? Ko : Vo;
            const float scl = (which == 0) ? 0.125f : 1.f;
#pragma unroll
            for (int im = 0; im < 4; ++im) {
                const int Rb2 = rb + wm * 64 + im * 16 + q * 4;
#pragma unroll
                for (int reg = 0; reg < 4; ++reg) {
                    const int R = Rb2 + reg;
                    if (R < kNT) {
                        const int bidx = R / 1025, nn = R - bidx * 1025;
                        dst[((size_t)(bidx * 12 + h) * 1025 + nn) * 64 + d0] =
                            __float2half_rn((acc[im][in][reg] + bcol[in]) * scl);
                    }
                }
            }
        }
    } else {
#pragma unroll
        for (int im = 0; im < 4; ++im) {
            const int Rb2 = rb + wm * 64 + im * 16 + q * 4;
#pragma unroll
            for (int reg = 0; reg < 4; ++reg) {
                const int R = Rb2 + reg;
                if (R < kNT) {
#pragma unroll
                    for (int in = 0; in < 4; ++in) {
                        const int Ncol = cb + wn * 64 + in * 16 + ln;
                        OutF[(size_t)R * 768 + Ncol] = acc[im][in][reg] + bcol[in];
                    }
                }
            }
        }
    }
}

// ---------------- K2: landmark pooling (fp16 src -> fp32 landmarks) ---------
__global__ __launch_bounds__(64) void pool_kernel(
    const __half* __restrict__ Qh, const __half* __restrict__ Kh,
    float* __restrict__ QM, float* __restrict__ KM)
{
    const int d  = threadIdx.x;
    const int m  = blockIdx.x;
    const int bh = blockIdx.y;
    const __half* sb = (blockIdx.z ? Kh : Qh) + (size_t)bh * kN * 64;
    float* dst = blockIdx.z ? KM : QM;
    float v;
    if (m == 0) {
        v = __half2float(sb[d]);
    } else {
        int l = m - 1, a = l >> 3, e = l & 7;
        const __half* base = sb + (size_t)(1 + a * 128 + e * 4) * 64 + d;
        float s = 0.f;
#pragma unroll
        for (int b4 = 0; b4 < 4; ++b4)
#pragma unroll
            for (int f = 0; f < 4; ++f)
                s += __half2float(base[(b4 * 32 + f) * 64]);
        v = s * 0.0625f;
    }
    dst[(size_t)bh * 65 * 64 + m * 64 + d] = v;
}

// ---------------- K3: t1 split — online-softmax S_C -> partial T1 + m_run ---
// grid(384, 6) block 256.  Outputs PT1[bh][sp][65*65], PM[bh][sp][65].
__global__ __launch_bounds__(256) void t1_split_kernel(
    const float* __restrict__ QM, const __half* __restrict__ Kg,
    const __half* __restrict__ Vg,
    float* __restrict__ PT1, float* __restrict__ PM)
{
    __shared__ _Float16 Qm16[65][68];   // [m][d]
    __shared__ _Float16 KV16[65][68];   // phase1: K [n][d]; phase2: Vaug [d|1][nn]
    __shared__ _Float16 ET16[65][68];   // P tile [m][nn]
    __shared__ float red[65][17];
    __shared__ float mrun[65], scal[65];
    const int t = threadIdx.x, bh = blockIdx.x, sp = blockIdx.y;
    const int tm = t >> 4, tn = t & 15;
    const float* qm = QM + (size_t)bh * 4160;
    const __half* Kb = Kg + (size_t)bh * 65600;
    const __half* Vb = Vg + (size_t)bh * 65600;

    for (int idx = t; idx < 4160; idx += 256)
        Qm16[idx >> 6][idx & 63] = (_Float16)qm[idx];
    if (t < 65) mrun[t] = -3.4e38f;

    float acc2[5][5];
#pragma unroll
    for (int i = 0; i < 5; ++i)
#pragma unroll
        for (int j = 0; j < 5; ++j) acc2[i][j] = 0.f;

    const int t0  = sp * 3;
    const int t1e = (t0 + 3 < 17) ? t0 + 3 : 17;

    for (int nt = t0; nt < t1e; ++nt) {
        const int n0 = nt * 64;
        __syncthreads();
        // stage K tile [n][d] fp16
#pragma unroll
        for (int s = 0; s < 2; ++s) {
            int idx = t + s * 256;              // 512 chunks of 8 halves
            int r = idx >> 3, c8 = (idx & 7) * 8;
            uint4 v = make_uint4(0u, 0u, 0u, 0u);
            if (n0 + r < kN) v = *(const uint4*)(Kb + (size_t)(n0 + r) * 64 + c8);
            uint* d = (uint*)&KV16[r][c8];
            d[0] = v.x; d[1] = v.y; d[2] = v.z; d[3] = v.w;
        }
        __syncthreads();
        // phase1: S = Qm @ K^T  (fdot2)
        float S[5][4];
#pragma unroll
        for (int i = 0; i < 5; ++i)
#pragma unroll
            for (int j = 0; j < 4; ++j) S[i][j] = 0.f;
#pragma unroll
        for (int kq = 0; kq < 16; ++kq) {
            h4v a[5], b[4];
#pragma unroll
            for (int i = 0; i < 4; ++i) a[i] = *(const h4v*)&Qm16[tm * 4 + i][kq * 4];
            a[4] = *(const h4v*)&Qm16[64][kq * 4];
#pragma unroll
            for (int j = 0; j < 4; ++j) b[j] = *(const h4v*)&KV16[tn * 4 + j][kq * 4];
#pragma unroll
            for (int i = 0; i < 5; ++i)
#pragma unroll
                for (int j = 0; j < 4; ++j)
                    S[i][j] = fdot4f(a[i], b[j], S[i][j]);
        }
        // per-thread token max -> row max -> online update
        float tmax[5];
#pragma unroll
        for (int i = 0; i < 5; ++i) tmax[i] = -3.4e38f;
#pragma unroll
        for (int j = 0; j < 4; ++j) {
            if (n0 + tn * 4 + j < kN) {
#pragma unroll
                for (int i = 0; i < 5; ++i) tmax[i] = fmaxf(tmax[i], S[i][j]);
            }
        }
#pragma unroll
        for (int i = 0; i < 4; ++i) red[tm * 4 + i][tn] = tmax[i];
        if (tm == 0) red[64][tn] = tmax[4];
        __syncthreads();
        if (t < 65) {
            float v = red[t][0];
#pragma unroll
            for (int c = 1; c < 16; ++c) v = fmaxf(v, red[t][c]);
            float mo = mrun[t];
            float mn = fmaxf(mo, v);
            scal[t] = __expf(mo - mn);    // 0 on first tile
            mrun[t] = mn;
        }
        __syncthreads();
        // rescale accumulator; exp tile -> ET16 fp16
        float sci[5], mri[5];
#pragma unroll
        for (int i = 0; i < 4; ++i) { sci[i] = scal[tm * 4 + i]; mri[i] = mrun[tm * 4 + i]; }
        sci[4] = scal[64]; mri[4] = mrun[64];
#pragma unroll
        for (int i = 0; i < 5; ++i)
#pragma unroll
            for (int j = 0; j < 5; ++j) acc2[i][j] *= sci[i];
#pragma unroll
        for (int j = 0; j < 4; ++j) {
            bool valid = (n0 + tn * 4 + j) < kN;
#pragma unroll
            for (int i = 0; i < 4; ++i)
                ET16[tm * 4 + i][tn * 4 + j] =
                    (_Float16)(valid ? __expf(S[i][j] - mri[i]) : 0.f);
            if (tm == 0)
                ET16[64][tn * 4 + j] = (_Float16)(valid ? __expf(S[4][j] - mri[4]) : 0.f);
        }
        __syncthreads();
        // stage Vaug transposed: KV16[d][nn], row 64 = ones
        {
            int n_loc = t >> 2, d0 = (t & 3) * 16;
            uint4 v0 = make_uint4(0u, 0u, 0u, 0u), v1 = v0;
            if (n0 + n_loc < kN) {
                v0 = *(const uint4*)(Vb + (size_t)(n0 + n_loc) * 64 + d0);
                v1 = *(const uint4*)(Vb + (size_t)(n0 + n_loc) * 64 + d0 + 8);
            }
            union { uint4 u[2]; _Float16 h[16]; } tmp;
            tmp.u[0] = v0; tmp.u[1] = v1;
#pragma unroll
            for (int s2 = 0; s2 < 16; ++s2) KV16[d0 + s2][n_loc] = tmp.h[s2];
        }
        if (t < 64) KV16[64][t] = (_Float16)1.f;
        __syncthreads();
        // phase2: acc2 += P @ Vaug  (fdot2; k = nn)
#pragma unroll
        for (int kq = 0; kq < 16; ++kq) {
            h4v a[5], b[5];
#pragma unroll
            for (int i = 0; i < 4; ++i) a[i] = *(const h4v*)&ET16[tm * 4 + i][kq * 4];
            a[4] = *(const h4v*)&ET16[64][kq * 4];
#pragma unroll
            for (int j = 0; j < 4; ++j) b[j] = *(const h4v*)&KV16[tn * 4 + j][kq * 4];
            b[4] = *(const h4v*)&KV16[64][kq * 4];
#pragma unroll
            for (int i = 0; i < 5; ++i)
#pragma unroll
                for (int j = 0; j < 5; ++j)
                    acc2[i][j] = fdot4f(a[i], b[j], acc2[i][j]);
        }
    }
    // write partials
    float* dst = PT1 + ((size_t)bh * kSplits + sp) * 4225;
#pragma unroll
    for (int i = 0; i < 5; ++i) {
        if (i == 4 && tm != 0) continue;
        int mi = (i < 4) ? tm * 4 + i : 64;
#pragma unroll
        for (int j = 0; j < 5; ++j) {
            if (j == 4 && tn != 0) continue;
            int jc = (j < 4) ? tn * 4 + j : 64;
            dst[mi * 65 + jc] = acc2[i][j];
        }
    }
    if (t < 65) PM[((size_t)bh * kSplits + sp) * 65 + t] = mrun[t];
}

// ---------------- K3b: combine partials -> T1, MAXC -------------------------
__global__ __launch_bounds__(256) void t1_reduce_kernel(
    const float* __restrict__ PT1, const float* __restrict__ PM,
    float* __restrict__ T1, float* __restrict__ MAXC)
{
    __shared__ float pm6[kSplits][65];
    __shared__ float sc6[kSplits][65];
    const int t = threadIdx.x, bh = blockIdx.x;
    for (int idx = t; idx < kSplits * 65; idx += 256)
        pm6[idx / 65][idx % 65] = PM[(size_t)bh * kSplits * 65 + idx];
    __syncthreads();
    if (t < 65) {
        float m = pm6[0][t];
#pragma unroll
        for (int sp = 1; sp < kSplits; ++sp) m = fmaxf(m, pm6[sp][t]);
        MAXC[(size_t)bh * 65 + t] = m;
#pragma unroll
        for (int sp = 0; sp < kSplits; ++sp) sc6[sp][t] = __expf(pm6[sp][t] - m);
    }
    __syncthreads();
    for (int o = t; o < 4225; o += 256) {
        int m = o / 65;
        float s = 0.f;
#pragma unroll
        for (int sp = 0; sp < kSplits; ++sp)
            s += sc6[sp][m] * PT1[((size_t)bh * kSplits + sp) * 4225 + o];
        T1[(size_t)bh * 4225 + o] = s;
    }
}

// ---------------- K4: expB = exp(max(qm@km^T - maxC, -88)); row/col maxima --
__global__ __launch_bounds__(256) void expb_kernel(
    const float* __restrict__ QM, const float* __restrict__ KM,
    const float* __restrict__ MAXC, float* __restrict__ EXPB,
    float* __restrict__ RC)
{
    __shared__ float Qs[65][68];
    __shared__ float Ks[65][68];
    __shared__ float SB[65][68];
    __shared__ float mc[65];
    __shared__ float rs[65], cs[65];
    const int t = threadIdx.x, bh = blockIdx.x;
    const float* qm = QM + (size_t)bh * 4160;
    const float* km = KM + (size_t)bh * 4160;
    for (int s = 0; s < 5; ++s) {
        int idx = t + s * 256;
        if (idx < 1040) {
            int r = idx >> 4, c = (idx & 15) * 4;
            *(float4*)&Qs[r][c] = *(const float4*)(qm + r * 64 + c);
            *(float4*)&Ks[r][c] = *(const float4*)(km + r * 64 + c);
        }
    }
    if (t < 65) mc[t] = MAXC[(size_t)bh * 65 + t];
    __syncthreads();
    for (int s = 0; s < 17; ++s) {
        int o = t + s * 256;
        if (o < 4225) {
            int i = o / 65, j = o % 65;
            float av = 0.f;
            for (int k = 0; k < 64; k += 4) {
                float4 a = *(const float4*)&Qs[i][k];
                float4 b = *(const float4*)&Ks[j][k];
                av = fmaf(a.x, b.x, av); av = fmaf(a.y, b.y, av);
                av = fmaf(a.z, b.z, av); av = fmaf(a.w, b.w, av);
            }
            float e = __expf(fmaxf(av - mc[i], -88.f));
            SB[i][j] = e;
            EXPB[(size_t)bh * 4225 + o] = e;
        }
    }
    __syncthreads();
    if (t < 65) {
        float r = 0.f, c = 0.f;
        for (int j = 0; j < 65; ++j) r += SB[t][j];
        for (int i = 0; i < 65; ++i) c += SB[i][t];
        rs[t] = r; cs[t] = c;
    }
    __syncthreads();
    if (t == 0) {
        float rm = 0.f, cm2 = 0.f;
        for (int i = 0; i < 65; ++i) { rm = fmaxf(rm, rs[i]); cm2 = fmaxf(cm2, cs[i]); }
        RC[bh * 2] = rm; RC[bh * 2 + 1] = cm2;
    }
}

// ---------------- K5: alpha = 1/(global_max_rowsum * global_max_colsum + eps)
__global__ __launch_bounds__(256) void alpha_kernel(
    const float* __restrict__ RC, float* __restrict__ GMX)
{
    __shared__ float sr[256], sc[256];
    const int t = threadIdx.x;
    float rm = 0.f, cm = 0.f;
    for (int i = t; i < kBH; i += 256) {
        rm = fmaxf(rm, RC[2 * i]);
        cm = fmaxf(cm, RC[2 * i + 1]);
    }
    sr[t] = rm; sc[t] = cm;
    __syncthreads();
    for (int s = 128; s > 0; s >>= 1) {
        if (t < s) { sr[t] = fmaxf(sr[t], sr[t + s]); sc[t] = fmaxf(sc[t], sc[t + s]); }
        __syncthreads();
    }
    if (t == 0) GMX[0] = 1.f / (sr[0] * sc[0] + 1e-15f);
}

// ---------------- K6: Newton-Schulz pinv (6 iters) + T2 = Z @ T1 ------------
__device__ __forceinline__ void mm65(const float (*Op1)[68], const float (*Op2)[68],
                                     float (*Dst)[68], const float (*Pre)[68],
                                     float c0, float c1, int tm, int tj)
{
    float acc[5][5];
#pragma unroll
    for (int i = 0; i < 5; ++i)
#pragma unroll
        for (int j = 0; j < 5; ++j) acc[i][j] = 0.f;
    for (int k = 0; k < 65; ++k) {
        float a[5], b[5];
        a[0] = Op1[tm * 4 + 0][k]; a[1] = Op1[tm * 4 + 1][k];
        a[2] = Op1[tm * 4 + 2][k]; a[3] = Op1[tm * 4 + 3][k];
        a[4] = (tm == 0) ? Op1[64][k] : 0.f;
        float4 bv = *(const float4*)&Op2[k][tj * 4];
        b[0] = bv.x; b[1] = bv.y; b[2] = bv.z; b[3] = bv.w;
        b[4] = (tj == 0) ? Op2[k][64] : 0.f;
#pragma unroll
        for (int i = 0; i < 5; ++i)
#pragma unroll
            for (int j = 0; j < 5; ++j)
                acc[i][j] = fmaf(a[i], b[j], acc[i][j]);
    }
    float val[5][5];
#pragma unroll
    for (int i = 0; i < 5; ++i) {
        int mi = (i < 4) ? tm * 4 + i : 64;
#pragma unroll
        for (int j = 0; j < 5; ++j) {
            int jc = (j < 4) ? tj * 4 + j : 64;
            val[i][j] = c1 * (c0 * Pre[mi][jc] - acc[i][j]);
        }
    }
    __syncthreads();
#pragma unroll
    for (int i = 0; i < 5; ++i) {
        if (i == 4 && tm != 0) continue;
        int mi = (i < 4) ? tm * 4 + i : 64;
#pragma unroll
        for (int j = 0; j < 5; ++j) {
            if (j == 4 && tj != 0) continue;
            int jc = (j < 4) ? tj * 4 + j : 64;
            Dst[mi][jc] = val[i][j];
        }
    }
    __syncthreads();
}

__global__ __launch_bounds__(256) void pinv_kernel(
    const float* __restrict__ EXPB, const float* __restrict__ T1,
    const float* __restrict__ GMX, float* __restrict__ T2)
{
    __shared__ float Wb[65][68];
    __shared__ float Zb[65][68];
    __shared__ float Ab[65][68];
    const int t = threadIdx.x, bh = blockIdx.x;
    const int tm = t >> 4, tj = t & 15;
    const float alpha = GMX[0];
    const float* X = EXPB + (size_t)bh * 4225;
    for (int s = 0; s < 17; ++s) {
        int o = t + s * 256;
        if (o < 4225) Wb[o / 65][o % 65] = X[o];
    }
    __syncthreads();
    for (int s = 0; s < 17; ++s) {   // Z = alpha * X^T
        int o = t + s * 256;
        if (o < 4225) { int i = o / 65, j = o % 65; Zb[i][j] = alpha * Wb[j][i]; }
    }
    __syncthreads();
    for (int it = 0; it < 6; ++it) {
        if (it > 0) {
            for (int s = 0; s < 17; ++s) {
                int o = t + s * 256;
                if (o < 4225) Wb[o / 65][o % 65] = X[o];
            }
            __syncthreads();
        }
        mm65(Wb, Zb, Ab, Wb, 0.f,  -1.f,  tm, tj);
        mm65(Ab, Ab, Wb, Ab, 7.f,   1.f,  tm, tj);
        mm65(Ab, Wb, Ab, Ab, 15.f,  1.f,  tm, tj);
        mm65(Zb, Ab, Zb, Zb, 13.f,  0.25f, tm, tj);
    }
    for (int s = 0; s < 17; ++s) {
        int o = t + s * 256;
        if (o < 4225) Wb[o / 65][o % 65] = T1[(size_t)bh * 4225 + o];
    }
    __syncthreads();
    {
        float acc[5][5];
#pragma unroll
        for (int i = 0; i < 5; ++i)
#pragma unroll
            for (int j = 0; j < 5; ++j) acc[i][j] = 0.f;
        for (int k = 0; k < 65; ++k) {
            float a[5], b[5];
            a[0] = Zb[tm * 4 + 0][k]; a[1] = Zb[tm * 4 + 1][k];
            a[2] = Zb[tm * 4 + 2][k]; a[3] = Zb[tm * 4 + 3][k];
            a[4] = (tm == 0) ? Zb[64][k] : 0.f;
            float4 bv = *(const float4*)&Wb[k][tj * 4];
            b[0] = bv.x; b[1] = bv.y; b[2] = bv.z; b[3] = bv.w;
            b[4] = (tj == 0) ? Wb[k][64] : 0.f;
#pragma unroll
            for (int i = 0; i < 5; ++i)
#pragma unroll
                for (int j = 0; j < 5; ++j)
                    acc[i][j] = fmaf(a[i], b[j], acc[i][j]);
        }
        float* dst = T2 + (size_t)bh * 4225;
#pragma unroll
        for (int i = 0; i < 5; ++i) {
            if (i == 4 && tm != 0) continue;
            int mi = (i < 4) ? tm * 4 + i : 64;
#pragma unroll
            for (int j = 0; j < 5; ++j) {
                if (j == 4 && tj != 0) continue;
                int jc = (j < 4) ? tj * 4 + j : 64;
                dst[mi * 65 + jc] = acc[i][j];
            }
        }
    }
}

// ---------------- K8: prod = expA @ T2 ; ctx -> fp16 (B,N,C) ----------------
// phase1 fdot2 on fp16 LDS (Km16/Qt16), phase2 fp32 (T2s unions with phase1).
__global__ __launch_bounds__(256) void prod_kernel(
    const __half* __restrict__ Qg, const float* __restrict__ KM,
    const float* __restrict__ T2, __half* __restrict__ CTXh)
{
    __shared__ __align__(16) char uni[17680];   // max(Km16+Qt16, T2s)
    _Float16 (*Km16)[68] = (_Float16(*)[68])uni;            // 65*68*2 = 8840
    _Float16 (*Qt16)[68] = (_Float16(*)[68])(uni + 8840);   // 64*68*2 = 8704
    float (*T2s)[68] = (float(*)[68])uni;                   // 65*68*4 = 17680
    __shared__ float EA[64][69];
    __shared__ float den[64];
    __shared__ float pm[64][4];
    const int t  = threadIdx.x;
    const int nt = blockIdx.x, bh = blockIdx.y;
    const int bq = bh / 12, h = bh % 12;
    const int n0 = nt * 64;
    const float* km = KM + (size_t)bh * 4160;
    const __half* Qb = Qg + (size_t)bh * 65600;

    for (int idx = t; idx < 4160; idx += 256)
        Km16[idx >> 6][idx & 63] = (_Float16)km[idx];
#pragma unroll
    for (int s = 0; s < 2; ++s) {
        int idx = t + s * 256;
        int r = idx >> 3, c8 = (idx & 7) * 8;
        uint4 v = make_uint4(0u, 0u, 0u, 0u);
        if (n0 + r < kN) v = *(const uint4*)(Qb + (size_t)(n0 + r) * 64 + c8);
        uint* d = (uint*)&Qt16[r][c8];
        d[0] = v.x; d[1] = v.y; d[2] = v.z; d[3] = v.w;
    }
    __syncthreads();
    {   // phase1: raw S_A tile via fdot2 (i -> landmark m, j -> token nn)
        const int tm = t >> 4, tn = t & 15;
        float acc[5][4];
#pragma unroll
        for (int i = 0; i < 5; ++i)
#pragma unroll
            for (int j = 0; j < 4; ++j) acc[i][j] = 0.f;
#pragma unroll
        for (int kq = 0; kq < 16; ++kq) {
            h4v a[5], b[4];
#pragma unroll
            for (int i = 0; i < 4; ++i) a[i] = *(const h4v*)&Km16[tm * 4 + i][kq * 4];
            a[4] = *(const h4v*)&Km16[64][kq * 4];
#pragma unroll
            for (int j = 0; j < 4; ++j) b[j] = *(const h4v*)&Qt16[tn * 4 + j][kq * 4];
#pragma unroll
            for (int i = 0; i < 5; ++i)
#pragma unroll
                for (int j = 0; j < 4; ++j)
                    acc[i][j] = fdot4f(a[i], b[j], acc[i][j]);
        }
#pragma unroll
        for (int j = 0; j < 4; ++j) {
            int nn = tn * 4 + j;
#pragma unroll
            for (int i = 0; i < 4; ++i) EA[nn][tm * 4 + i] = acc[i][j];
            if (tm == 0) EA[nn][64] = acc[4][j];
        }
    }
    __syncthreads();
    {   // row max + exp (per token over 65 landmarks)
        const int rr = t & 63, mg = t >> 6;
        float mx = -3.4e38f;
        for (int s = 0; s < 17; ++s) { int m = mg + 4 * s; if (m < 65) mx = fmaxf(mx, EA[rr][m]); }
        pm[rr][mg] = mx;
        __syncthreads();
        float mt2 = fmaxf(fmaxf(pm[rr][0], pm[rr][1]), fmaxf(pm[rr][2], pm[rr][3]));
        for (int s = 0; s < 17; ++s) { int m = mg + 4 * s; if (m < 65) EA[rr][m] = __expf(EA[rr][m] - mt2); }
    }
    for (int s = 0; s < 17; ++s) {   // stage T2 (overwrites Km16/Qt16; phase1 done)
        int o = t + s * 256;
        if (o < 4225) T2s[o / 65][o % 65] = T2[(size_t)bh * 4225 + o];
    }
    __syncthreads();
    {   // phase2: prod = EA @ T2 (fp32), divide, stash ctx tile
        const int tr = t & 15, tjg = t >> 4;
        float acc2[4][5];
#pragma unroll
        for (int i = 0; i < 4; ++i)
#pragma unroll
            for (int j = 0; j < 5; ++j) acc2[i][j] = 0.f;
        for (int m = 0; m < 65; ++m) {
            float a[4], b[5];
            a[0] = EA[tr * 4 + 0][m]; a[1] = EA[tr * 4 + 1][m];
            a[2] = EA[tr * 4 + 2][m]; a[3] = EA[tr * 4 + 3][m];
            float4 bv = *(const float4*)&T2s[m][tjg * 4];
            b[0] = bv.x; b[1] = bv.y; b[2] = bv.z; b[3] = bv.w;
            b[4] = (tjg == 0) ? T2s[m][64] : 0.f;
#pragma unroll
            for (int i = 0; i < 4; ++i)
#pragma unroll
                for (int j = 0; j < 5; ++j)
                    acc2[i][j] = fmaf(a[i], b[j], acc2[i][j]);
        }
        if (tjg == 0) {
#pragma unroll
            for (int ii = 0; ii < 4; ++ii) den[tr * 4 + ii] = acc2[ii][4];
        }
        __syncthreads();
#pragma unroll
        for (int ii = 0; ii < 4; ++ii) {
            int nn = tr * 4 + ii;
            float dv = fmaxf(den[nn], 1e-8f);
#pragma unroll
            for (int jj = 0; jj < 4; ++jj)
                EA[nn][tjg * 4 + jj] = acc2[ii][jj] / dv;
        }
    }
    __syncthreads();
    {   // write ctx fp16: [b, n, h*64 + c]
        const int c = t & 63, rg = t >> 6;
        for (int s = 0; s < 16; ++s) {
            int r = rg + 4 * s;
            int n = n0 + r;
            if (n < kN)
                CTXh[((size_t)bq * 1025 + n) * 768 + h * 64 + c] = __float2half_rn(EA[r][c]);
        }
    }
}

// ---------------------------------------------------------------------------
extern "C" void kernel_launch(void* const* d_in, const int* in_sizes, int n_in,
                              void* d_out, int out_size, void* d_ws, size_t ws_size,
                              hipStream_t stream)
{
    const float* x      = (const float*)d_in[0];
    const float* qkv_w  = (const float*)d_in[1];
    const float* qkv_b  = (const float*)d_in[2];
    const float* proj_w = (const float*)d_in[3];
    const float* proj_b = (const float*)d_in[4];
    float* out = (float*)d_out;

    // d_out: [Xh (QSZ halves) | Qh (QSZ halves)].
    // Xh region is reused (after gemm_qkv) for t1 partials: PT1 | PM.
    __half* Xh = (__half*)d_out;
    __half* Qh = Xh + QSZ;
    float* PT1 = (float*)d_out;                       // 6*384*4225 = 9,734,400 f
    float* PM  = PT1 + (size_t)kSplits * kBH * 4225;  //   149,760 f  (< QSZ/2 total)

    // ws layout
    __half* Kh   = (__half*)d_ws;               // QSZ halves
    __half* Vh   = Kh + QSZ;                    // QSZ halves
    __half* CTXh = Kh;                          // aliases Kh (dead after t1)
    float*  QM   = (float*)(Vh + QSZ);
    float*  KM   = QM + QMSZ;
    float*  MAXC = KM + QMSZ;
    float*  EXPB = MAXC + (size_t)kBH * 65;
    float*  T1   = EXPB + SBSZ;
    float*  T2   = T1 + SBSZ;
    float*  RC   = T2 + SBSZ;
    float*  GMX  = RC + (size_t)kBH * 2;
    size_t woff = (size_t)(GMX + 1 - (float*)d_ws);
    woff = (woff + 3) & ~(size_t)3;
    __half* WqkvT  = (__half*)((float*)d_ws + woff);  // 2304*768 halves
    __half* WprojT = WqkvT + (size_t)2304 * 768;      // 768*768 halves

    cvt_f32_f16  <<<dim3((int)(QSZ / 4 / 256)), 256, 0, stream>>>(x, Xh, (int)(QSZ / 4));
    cvt_transpose<<<dim3(72, 24), dim3(32, 8), 0, stream>>>(qkv_w, WqkvT, 768, 2304);
    cvt_transpose<<<dim3(24, 24), dim3(32, 8), 0, stream>>>(proj_w, WprojT, 768, 768);

    gemm_mfma<0><<<dim3(18, 257), 256, 0, stream>>>(Xh, WqkvT, qkv_b,
                                                    nullptr, Qh, Kh, Vh);
    pool_kernel<<<dim3(65, kBH, 2), 64, 0, stream>>>(Qh, Kh, QM, KM);
    t1_split_kernel <<<dim3(kBH, kSplits), 256, 0, stream>>>(QM, Kh, Vh, PT1, PM);
    t1_reduce_kernel<<<dim3(kBH), 256, 0, stream>>>(PT1, PM, T1, MAXC);
    expb_kernel<<<dim3(kBH), 256, 0, stream>>>(QM, KM, MAXC, EXPB, RC);
    alpha_kernel<<<dim3(1), 256, 0, stream>>>(RC, GMX);
    pinv_kernel<<<dim3(kBH), 256, 0, stream>>>(EXPB, T1, GMX, T2);
    prod_kernel<<<dim3(17, kBH), 256, 0, stream>>>(Qh, KM, T2, CTXh);
    gemm_mfma<1><<<dim3(6, 257), 256, 0, stream>>>(CTXh, WprojT, proj_b,
                                                   out, nullptr, nullptr, nullptr);
}